// Round 5
// baseline (358.559 us; speedup 1.0000x reference)
//
#include <hip/hip_runtime.h>
#include <hip/hip_bf16.h>
#include <stdint.h>

// ---------------------------------------------------------------------------
// W8A16 linear: out[M,N] = (A[M,K] fp32) x (W[N,K] int8->bf16)^T * scales[N] + bias[N]
// M=8192, N=4096, K=4096.  Prepass converts A,W -> bf16 in d_ws, then a
// 256x256-tile GEMM. R5: lookahead pipeline — B-frags for tile u+1 pre-read
// at tile u's ph4 (ping-pong regs), counted lgkm waits so DS drains under
// MFMA, precomputed swizzled LDS read bases (no per-phase addr VALU).
// ---------------------------------------------------------------------------

typedef __attribute__((ext_vector_type(8))) short bf16x8;
typedef __attribute__((ext_vector_type(4))) float f32x4;
typedef __attribute__((ext_vector_type(8))) unsigned short u16x8;

__device__ __forceinline__ unsigned short f2bf(float x) {
  union { float f; unsigned u; } v; v.f = x;
  unsigned u = v.u;
  return (unsigned short)((u + 0x7FFFu + ((u >> 16) & 1u)) >> 16); // RNE
}

__global__ __launch_bounds__(256) void cvt_a_kernel(const float* __restrict__ in,
                                                    unsigned short* __restrict__ out) {
  long i = (long)blockIdx.x * 256 + threadIdx.x;
  const float4* in4 = (const float4*)in;
  float4 a = in4[2 * i];
  float4 b = in4[2 * i + 1];
  u16x8 r;
  r[0] = f2bf(a.x); r[1] = f2bf(a.y); r[2] = f2bf(a.z); r[3] = f2bf(a.w);
  r[4] = f2bf(b.x); r[5] = f2bf(b.y); r[6] = f2bf(b.z); r[7] = f2bf(b.w);
  ((u16x8*)out)[i] = r;
}

__global__ __launch_bounds__(256) void cvt_w_kernel(const int* __restrict__ in,
                                                    unsigned short* __restrict__ out) {
  long i = (long)blockIdx.x * 256 + threadIdx.x;
  int4 a = ((const int4*)in)[2 * i];
  int4 b = ((const int4*)in)[2 * i + 1];
  u16x8 r;
  r[0] = f2bf((float)a.x); r[1] = f2bf((float)a.y);
  r[2] = f2bf((float)a.z); r[3] = f2bf((float)a.w);
  r[4] = f2bf((float)b.x); r[5] = f2bf((float)b.y);
  r[6] = f2bf((float)b.z); r[7] = f2bf((float)b.w);
  ((u16x8*)out)[i] = r;
}

__device__ __forceinline__ void gl_lds16(const void* g, void* l) {
  __builtin_amdgcn_global_load_lds(
      (const __attribute__((address_space(1))) void*)g,
      (__attribute__((address_space(3))) void*)l,
      16, 0, 0);
}

__device__ __forceinline__ void stage2(const unsigned short* src, size_t K8,
                                       unsigned short* dst) {
  gl_lds16(src, dst);
  gl_lds16(src + K8, dst + 512);
}

#define WAIT_LGKM(N) do { asm volatile("s_waitcnt lgkmcnt(" #N ")" ::: "memory"); \
                          __builtin_amdgcn_sched_barrier(0); } while (0)
#define WAIT_VM(N)   asm volatile("s_waitcnt vmcnt(" #N ")" ::: "memory")
#define BAR()        do { asm volatile("" ::: "memory"); \
                          __builtin_amdgcn_s_barrier(); \
                          asm volatile("" ::: "memory"); } while (0)

#define BM 256
#define BN 256
#define BKT 64
#define HELEMS (128 * 64)   // one half-tile: 128 rows x 64 k = 16 KB (16384 B)

template <int MI0>
__device__ __forceinline__ void mfma_quad(f32x4 (&acc)[8][4],
                                          const bf16x8 (&a)[2][2],
                                          const bf16x8 (&b)[4][2]) {
  __builtin_amdgcn_s_setprio(1);
#pragma unroll
  for (int m = 0; m < 2; ++m)
#pragma unroll
    for (int ni = 0; ni < 4; ++ni)
#pragma unroll
      for (int kk = 0; kk < 2; ++kk)
        acc[MI0 + m][ni] = __builtin_amdgcn_mfma_f32_16x16x32_bf16(
            a[m][kk], b[ni][kk], acc[MI0 + m][ni], 0, 0, 0);
  __builtin_amdgcn_s_setprio(0);
}

// A-quad read: 4 ds_read_b128 at base + compile-time immediates
#define RD_AQ(dst, Pq, MI0)                                                  \
  do {                                                                       \
    dst[0][0] = *(const bf16x8*)(ldsB + offA[Pq][0] + (MI0) * 2048);         \
    dst[0][1] = *(const bf16x8*)(ldsB + offA[Pq][1] + (MI0) * 2048);         \
    dst[1][0] = *(const bf16x8*)(ldsB + offA[Pq][0] + (MI0 + 1) * 2048);     \
    dst[1][1] = *(const bf16x8*)(ldsB + offA[Pq][1] + (MI0 + 1) * 2048);     \
  } while (0)

// One K-tile, 4 phases. Reads: ph1 a0,a1,a2 (12); ph2 a3 (4); ph3 none;
// ph4 (after vmcnt+BAR) next tile's B-frags (8) into BFRN.
// Stages: ph1 A1(u+1); ph2 B0(u+2); ph3 B1(u+2); ph4 A0(u+2).
// Hazard ledger (all verified): every LDS region staged in phase q had all
// its readers' lgkm-drained + barrier before q; every region read at ph4's
// lookahead had its DMA covered by vmcnt(6)+BAR.
#define KTILE(U, P, TAIL, BFRC, BFRN)                                         \
  do {                                                                        \
    const int u_ = (U);                                                       \
    bf16x8 a0[2][2], a1[2][2], a2[2][2], a3[2][2];                            \
    /* ---- ph1 ---- */                                                       \
    RD_AQ(a0, P, 0);                                                          \
    __builtin_amdgcn_sched_barrier(0); /* pin a0 reads oldest */              \
    RD_AQ(a1, P, 2);                                                          \
    RD_AQ(a2, P, 4);                                                          \
    if (!(TAIL) || u_ + 1 < NT)                                               \
      stage2(gA_lane + K128 + (size_t)(u_ + 1) * BKT, K8,                     \
             (unsigned short*)(ldsB + (((P ^ 1) * 4 + 1) * 16384) + stOffB)); \
    BAR();                                                                    \
    if (TAIL) { WAIT_LGKM(0); } else { WAIT_LGKM(8); }                        \
    mfma_quad<0>(acc, a0, BFRC);                                              \
    BAR();                                                                    \
    /* ---- ph2 ---- */                                                       \
    RD_AQ(a3, P, 6);                                                          \
    if (!(TAIL) || u_ + 2 < NT)                                               \
      stage2(gB_lane + (size_t)(u_ + 2) * BKT, K8,                            \
             (unsigned short*)(ldsB + (((P) * 4 + 2) * 16384) + stOffB));     \
    BAR();                                                                    \
    if (TAIL) { WAIT_LGKM(0); } else { WAIT_LGKM(4); }                        \
    mfma_quad<2>(acc, a1, BFRC);                                              \
    BAR();                                                                    \
    /* ---- ph3 ---- */                                                       \
    if (!(TAIL) || u_ + 2 < NT)                                               \
      stage2(gB_lane + K128 + (size_t)(u_ + 2) * BKT, K8,                     \
             (unsigned short*)(ldsB + (((P) * 4 + 3) * 16384) + stOffB));     \
    BAR();                                                                    \
    WAIT_LGKM(0); /* drains a2 (consumed now) AND a3 (before ph4 stage) */    \
    mfma_quad<4>(acc, a2, BFRC);                                              \
    BAR();                                                                    \
    /* ---- ph4 ---- */                                                       \
    if (!(TAIL) || u_ + 2 < NT)                                               \
      stage2(gA_lane + (size_t)(u_ + 2) * BKT, K8,                            \
             (unsigned short*)(ldsB + (((P) * 4 + 0) * 16384) + stOffB));     \
    if (TAIL) { WAIT_VM(0); } else { WAIT_VM(6); }                            \
    BAR();                                                                    \
    if (!(TAIL) || u_ + 1 < NT) {                                             \
      _Pragma("unroll")                                                       \
      for (int ni = 0; ni < 4; ++ni) {                                        \
        BFRN[ni][0] = *(const bf16x8*)(ldsB + offB[(P) ^ 1][0] + ni * 2048);  \
        BFRN[ni][1] = *(const bf16x8*)(ldsB + offB[(P) ^ 1][1] + ni * 2048);  \
      }                                                                       \
    }                                                                         \
    if (TAIL) { WAIT_LGKM(0); } else { WAIT_LGKM(8); }                        \
    mfma_quad<6>(acc, a3, BFRC);                                              \
    BAR();                                                                    \
  } while (0)

__global__ __launch_bounds__(512, 2) void gemm8_kernel(
    const unsigned short* __restrict__ A,   // [M,K] bf16
    const unsigned short* __restrict__ Wt,  // [N,K] bf16
    const float* __restrict__ scales,       // [N]
    const float* __restrict__ bias,         // [N]
    float* __restrict__ out,                // [M,N] fp32
    int M, int N, int K) {
  // [buf][A=0/B=1][half][128*64] ; byte off = (buf*4 + op*2 + half)*16384
  __shared__ unsigned short lds[2][2][2][HELEMS];
  char* ldsB = (char*)&lds[0][0][0][0];

  const int tid = threadIdx.x;
  const int lane = tid & 63;
  const int w = tid >> 6;      // wave 0..7
  const int wr = w >> 2;       // 0..1 (M)
  const int wc = w & 3;        // 0..3 (N)
  const int r = lane & 15;
  const int q4 = lane >> 4;
  const int NT = K / BKT;

  // Supertile XCD swizzle (per-XCD 1 tile_m x 16 tile_n strip)
  const int nm = M / BM, nn_t = N / BN;
  const int nwg = gridDim.x;
  const int bid = blockIdx.x;
  int tile_m, tile_n;
  if (nm == 32 && nn_t == 16 && nwg == 512) {
    int xcd = bid & 7;
    int j = bid >> 3;
    tile_m = (j >> 4) * 8 + xcd;
    tile_n = j & 15;
  } else {
    int swz = bid;
    if ((nwg & 7) == 0) swz = (bid & 7) * (nwg >> 3) + (bid >> 3);
    tile_m = swz % nm;
    tile_n = swz / nm;
  }
  const int bm = tile_m * BM;
  const int bn = tile_n * BN;

  // ---- precomputed swizzled LDS read bases (byte offsets from ldsB) ------
  // read addr = R16*128 + r*128 + ((q4^(r&3))<<4) + ((kk^((r>>2)&1))<<6)
  // == (row*128 + col) ^ ((row&7)<<4)  [verified algebraically]
  const int lk0 = r * 128 + ((q4 ^ (r & 3)) << 4) + ((((r >> 2) & 1)) << 6);
  const int lk1 = r * 128 + ((q4 ^ (r & 3)) << 4) + ((1 ^ ((r >> 2) & 1)) << 6);
  int offA[2][2], offB[2][2];
#pragma unroll
  for (int p = 0; p < 2; ++p) {
    offA[p][0] = (p * 4 + wr) * 16384 + lk0;
    offA[p][1] = (p * 4 + wr) * 16384 + lk1;
    offB[p][0] = (p * 4 + 2 + (wc >> 1)) * 16384 + (wc & 1) * 8192 + lk0;
    offB[p][1] = (p * 4 + 2 + (wc >> 1)) * 16384 + (wc & 1) * 8192 + lk1;
  }

  // ---- staging lane constants --------------------------------------------
  const int rl = lane >> 3;
  const int gs = (lane & 7) ^ (rl & 7);            // inverse-swizzled source
  const int stOffB = w * 2048 + lane * 16;         // LDS dest bytes (linear)
  const size_t K8 = (size_t)8 * K;
  const size_t K128 = (size_t)128 * K;
  const unsigned short* gA_lane = A + (size_t)bm * K + (size_t)(w * 16 + rl) * K + gs * 8;
  const unsigned short* gB_lane = Wt + (size_t)bn * K + (size_t)(w * 16 + rl) * K + gs * 8;

  // ---- prologue: tile0 {A0,A1,B0,B1}, tile1 {B0,B1,A0} -------------------
  stage2(gA_lane,              K8, (unsigned short*)(ldsB + 0 * 16384 + stOffB));
  stage2(gA_lane + K128,       K8, (unsigned short*)(ldsB + 1 * 16384 + stOffB));
  stage2(gB_lane,              K8, (unsigned short*)(ldsB + 2 * 16384 + stOffB));
  stage2(gB_lane + K128,       K8, (unsigned short*)(ldsB + 3 * 16384 + stOffB));
  stage2(gB_lane + BKT,        K8, (unsigned short*)(ldsB + 6 * 16384 + stOffB));
  stage2(gB_lane + K128 + BKT, K8, (unsigned short*)(ldsB + 7 * 16384 + stOffB));
  stage2(gA_lane + BKT,        K8, (unsigned short*)(ldsB + 4 * 16384 + stOffB));
  WAIT_VM(0);
  BAR();

  f32x4 acc[8][4] = {};
  bf16x8 bfrA[4][2], bfrB[4][2];

  // pre-read tile0's B frags (plays the role of "u=-1 ph4 lookahead")
#pragma unroll
  for (int ni = 0; ni < 4; ++ni) {
    bfrA[ni][0] = *(const bf16x8*)(ldsB + offB[0][0] + ni * 2048);
    bfrA[ni][1] = *(const bf16x8*)(ldsB + offB[0][1] + ni * 2048);
  }

  // ---- main loop (branch-free) + 2-tile tail -----------------------------
  for (int t = 0; t < NT - 2; t += 2) {
    KTILE(t,     0, 0, bfrA, bfrB);
    KTILE(t + 1, 1, 0, bfrB, bfrA);
  }
  KTILE(NT - 2, 0, 1, bfrA, bfrB);
  KTILE(NT - 1, 1, 1, bfrB, bfrA);

  // ---- epilogue: out = acc * scales + bias --------------------------------
  float sc[4], bs[4];
#pragma unroll
  for (int ni = 0; ni < 4; ++ni) {
    int col = bn + wc * 64 + ni * 16 + r;
    sc[ni] = scales[col];
    bs[ni] = bias[col];
  }
#pragma unroll
  for (int mi = 0; mi < 8; ++mi)
#pragma unroll
    for (int ni = 0; ni < 4; ++ni)
#pragma unroll
      for (int i = 0; i < 4; ++i) {
        int grow = bm + wr * 128 + mi * 16 + q4 * 4 + i;
        int gcol = bn + wc * 64 + ni * 16 + r;
        out[(size_t)grow * N + gcol] = acc[mi][ni][i] * sc[ni] + bs[ni];
      }
}

// ---- fallback (correct but slow) ------------------------------------------
__global__ __launch_bounds__(256) void naive_kernel(
    const float* __restrict__ A, const int* __restrict__ W8,
    const float* __restrict__ scales, const float* __restrict__ bias,
    float* __restrict__ out, int M, int N, int K) {
  long idx = (long)blockIdx.x * 256 + threadIdx.x;
  if (idx >= (long)M * N) return;
  int m = (int)(idx / N), n = (int)(idx % N);
  const float* a = A + (size_t)m * K;
  const int* wv = W8 + (size_t)n * K;
  float s = 0.f;
  for (int k = 0; k < K; ++k) s += a[k] * (float)wv[k];
  out[idx] = s * scales[n] + bias[n];
}

extern "C" void kernel_launch(void* const* d_in, const int* in_sizes, int n_in,
                              void* d_out, int out_size, void* d_ws, size_t ws_size,
                              hipStream_t stream) {
  const float* A = (const float*)d_in[0];
  const int* W8 = (const int*)d_in[1];
  const float* scales = (const float*)d_in[2];
  const float* bias = (const float*)d_in[3];
  float* out = (float*)d_out;

  const int N = in_sizes[2];
  const int K = in_sizes[1] / N;
  const int M = in_sizes[0] / K;

  size_t a_bytes = (size_t)M * K * 2;
  size_t w_bytes = (size_t)N * K * 2;
  const int NT = K / BKT;

  bool tiled_ok = (M % BM == 0) && (N % BN == 0) && (K % BKT == 0) &&
                  (NT >= 4) && (NT % 2 == 0) && (ws_size >= a_bytes + w_bytes);

  if (!tiled_ok) {
    long total = (long)M * N;
    naive_kernel<<<(unsigned)((total + 255) / 256), 256, 0, stream>>>(
        A, W8, scales, bias, out, M, N, K);
    return;
  }

  unsigned short* Abf = (unsigned short*)d_ws;
  unsigned short* Wbf = (unsigned short*)((char*)d_ws + a_bytes);

  long nA = (long)M * K;
  long nW = (long)N * K;
  cvt_a_kernel<<<(unsigned)(nA / 2048), 256, 0, stream>>>(A, Abf);
  cvt_w_kernel<<<(unsigned)(nW / 2048), 256, 0, stream>>>(W8, Wbf);

  unsigned nwg = (unsigned)((M / BM) * (N / BN));  // 512
  gemm8_kernel<<<nwg, 512, 0, stream>>>(Abf, Wbf, scales, bias, out, M, N, K);
}

// Round 6
// 285.659 us; speedup vs baseline: 1.2552x; 1.2552x over previous
//
#include <hip/hip_runtime.h>
#include <hip/hip_bf16.h>
#include <stdint.h>

// ---------------------------------------------------------------------------
// W8A16 linear: out[M,N] = (A[M,K] fp32) x (W[N,K] int8->bf16)^T * scales[N] + bias[N]
// M=8192, N=4096, K=4096.  Prepass converts A,W -> bf16 in d_ws, then a
// 256x256-tile GEMM. R6 = R4's proven schedule + A-quad lookahead with
// counted lgkm (quad for phase i read in phase i-1; quad0 of tile u+1 read
// at ph4 after vmcnt+BAR), B-frags single-buffered (register-pressure safe),
// precomputed swizzled LDS read bases.
// ---------------------------------------------------------------------------

typedef __attribute__((ext_vector_type(8))) short bf16x8;
typedef __attribute__((ext_vector_type(4))) float f32x4;
typedef __attribute__((ext_vector_type(8))) unsigned short u16x8;

__device__ __forceinline__ unsigned short f2bf(float x) {
  union { float f; unsigned u; } v; v.f = x;
  unsigned u = v.u;
  return (unsigned short)((u + 0x7FFFu + ((u >> 16) & 1u)) >> 16); // RNE
}

__global__ __launch_bounds__(256) void cvt_a_kernel(const float* __restrict__ in,
                                                    unsigned short* __restrict__ out) {
  long i = (long)blockIdx.x * 256 + threadIdx.x;
  const float4* in4 = (const float4*)in;
  float4 a = in4[2 * i];
  float4 b = in4[2 * i + 1];
  u16x8 r;
  r[0] = f2bf(a.x); r[1] = f2bf(a.y); r[2] = f2bf(a.z); r[3] = f2bf(a.w);
  r[4] = f2bf(b.x); r[5] = f2bf(b.y); r[6] = f2bf(b.z); r[7] = f2bf(b.w);
  ((u16x8*)out)[i] = r;
}

__global__ __launch_bounds__(256) void cvt_w_kernel(const int* __restrict__ in,
                                                    unsigned short* __restrict__ out) {
  long i = (long)blockIdx.x * 256 + threadIdx.x;
  int4 a = ((const int4*)in)[2 * i];
  int4 b = ((const int4*)in)[2 * i + 1];
  u16x8 r;
  r[0] = f2bf((float)a.x); r[1] = f2bf((float)a.y);
  r[2] = f2bf((float)a.z); r[3] = f2bf((float)a.w);
  r[4] = f2bf((float)b.x); r[5] = f2bf((float)b.y);
  r[6] = f2bf((float)b.z); r[7] = f2bf((float)b.w);
  ((u16x8*)out)[i] = r;
}

__device__ __forceinline__ void gl_lds16(const void* g, void* l) {
  __builtin_amdgcn_global_load_lds(
      (const __attribute__((address_space(1))) void*)g,
      (__attribute__((address_space(3))) void*)l,
      16, 0, 0);
}

__device__ __forceinline__ void stage2(const unsigned short* src, size_t K8,
                                       unsigned short* dst) {
  gl_lds16(src, dst);
  gl_lds16(src + K8, dst + 512);
}

#define WAIT_LGKM(N) do { asm volatile("s_waitcnt lgkmcnt(" #N ")" ::: "memory"); \
                          __builtin_amdgcn_sched_barrier(0); } while (0)
#define WAIT_VM(N)   asm volatile("s_waitcnt vmcnt(" #N ")" ::: "memory")
#define BAR()        do { asm volatile("" ::: "memory"); \
                          __builtin_amdgcn_s_barrier(); \
                          asm volatile("" ::: "memory"); } while (0)
#define SBAR0()      __builtin_amdgcn_sched_barrier(0)

#define BM 256
#define BN 256
#define BKT 64
#define HELEMS (128 * 64)   // one half-tile: 128 rows x 64 k = 16384 B

template <int MI0>
__device__ __forceinline__ void mfma_quad(f32x4 (&acc)[8][4],
                                          const bf16x8 (&a)[2][2],
                                          const bf16x8 (&b)[4][2]) {
  __builtin_amdgcn_s_setprio(1);
#pragma unroll
  for (int m = 0; m < 2; ++m)
#pragma unroll
    for (int ni = 0; ni < 4; ++ni)
#pragma unroll
      for (int kk = 0; kk < 2; ++kk)
        acc[MI0 + m][ni] = __builtin_amdgcn_mfma_f32_16x16x32_bf16(
            a[m][kk], b[ni][kk], acc[MI0 + m][ni], 0, 0, 0);
  __builtin_amdgcn_s_setprio(0);
}

// A-quad read (4 ds_read_b128 at precomputed base + compile-time immediates)
#define RD_AQ(dst, Pq, MI0)                                                  \
  do {                                                                       \
    dst[0][0] = *(const bf16x8*)(ldsB + offA[Pq][0] + (MI0) * 2048);         \
    dst[0][1] = *(const bf16x8*)(ldsB + offA[Pq][1] + (MI0) * 2048);         \
    dst[1][0] = *(const bf16x8*)(ldsB + offA[Pq][0] + (MI0 + 1) * 2048);     \
    dst[1][1] = *(const bf16x8*)(ldsB + offA[Pq][1] + (MI0 + 1) * 2048);     \
  } while (0)

// One K-tile, 4 phases, compile-time parity P. Lookahead: quad for phase i
// read at phase i-1 (counted lgkm(4)); quad0(u+1) read at ph4 post-vmcnt+BAR.
// Stages (same slots as R4): ph1 A1(u+1); ph2 B0(u+2); ph3 B1(u+2); ph4 A0(u+2).
// Hazards: every staged region's readers lgkm-drained + BAR'd strictly
// earlier (B(u) drained ph1; q3 drained ph3's lgkm(0) before ph4's A0 stage);
// vmcnt(6) at ph4 proves all of tile u+1 resident before its q0'/B reads.
#define KT(U, P)                                                              \
  do {                                                                        \
    const int u_ = (U);                                                       \
    /* ---- ph1: read B(8)+q1(4); stage A1(u+1) ---- */                       \
    _Pragma("unroll")                                                         \
    for (int ni = 0; ni < 4; ++ni) {                                          \
      bfr[ni][0] = *(const bf16x8*)(ldsB + offB[P][0] + ni * 2048);           \
      bfr[ni][1] = *(const bf16x8*)(ldsB + offB[P][1] + ni * 2048);           \
    }                                                                         \
    SBAR0(); /* pin: B reads issue before q1 reads (counted-lgkm order) */    \
    RD_AQ(aQ1, P, 2);                                                         \
    if (u_ + 1 < NT)                                                          \
      stage2(gA_lane + K128 + (size_t)(u_ + 1) * BKT, K8,                     \
             (unsigned short*)(ldsB + (((P ^ 1) * 4 + 1) * 16384) + stOffB)); \
    BAR();                                                                    \
    WAIT_LGKM(4); /* drain q0(4)+B(8), keep q1 in flight under MFMA */        \
    mfma_quad<0>(acc, aQ0, bfr);                                              \
    BAR();                                                                    \
    /* ---- ph2: read q2; stage B0(u+2) ---- */                               \
    RD_AQ(aQ2, P, 4);                                                         \
    if (u_ + 2 < NT)                                                          \
      stage2(gB_lane + (size_t)(u_ + 2) * BKT, K8,                            \
             (unsigned short*)(ldsB + (((P) * 4 + 2) * 16384) + stOffB));     \
    BAR();                                                                    \
    WAIT_LGKM(4); /* drain q1, keep q2 */                                     \
    mfma_quad<2>(acc, aQ1, bfr);                                              \
    BAR();                                                                    \
    /* ---- ph3: read q3; stage B1(u+2) ---- */                               \
    RD_AQ(aQ3, P, 6);                                                         \
    if (u_ + 2 < NT)                                                          \
      stage2(gB_lane + K128 + (size_t)(u_ + 2) * BKT, K8,                     \
             (unsigned short*)(ldsB + (((P) * 4 + 3) * 16384) + stOffB));     \
    BAR();                                                                    \
    WAIT_LGKM(0); /* drain q2 AND q3 (q3 must land before ph4's A0 stage) */  \
    mfma_quad<4>(acc, aQ2, bfr);                                              \
    BAR();                                                                    \
    /* ---- ph4: stage A0(u+2); vmcnt; BAR; read q0'(u+1) ---- */             \
    if (u_ + 2 < NT)                                                          \
      stage2(gA_lane + (size_t)(u_ + 2) * BKT, K8,                            \
             (unsigned short*)(ldsB + (((P) * 4 + 0) * 16384) + stOffB));     \
    if (u_ < NT - 1) {                                                        \
      if (u_ + 2 < NT) { WAIT_VM(6); } else { WAIT_VM(0); }                   \
    }                                                                         \
    BAR();                                                                    \
    if (u_ + 1 < NT) RD_AQ(aQ0, (P) ^ 1, 0);                                  \
    mfma_quad<6>(acc, aQ3, bfr);                                              \
    BAR();                                                                    \
  } while (0)

__global__ __launch_bounds__(512, 2) void gemm8_kernel(
    const unsigned short* __restrict__ A,   // [M,K] bf16
    const unsigned short* __restrict__ Wt,  // [N,K] bf16
    const float* __restrict__ scales,       // [N]
    const float* __restrict__ bias,         // [N]
    float* __restrict__ out,                // [M,N] fp32
    int M, int N, int K) {
  // [buf][A=0/B=1][half]; byte offset = (buf*4 + op*2 + half)*16384
  __shared__ unsigned short lds[2][2][2][HELEMS];
  char* ldsB = (char*)&lds[0][0][0][0];

  const int tid = threadIdx.x;
  const int lane = tid & 63;
  const int w = tid >> 6;      // wave 0..7
  const int wr = w >> 2;       // 0..1 (M)
  const int wc = w & 3;        // 0..3 (N)
  const int r = lane & 15;
  const int q4 = lane >> 4;
  const int NT = K / BKT;

  // Supertile XCD swizzle (per-XCD 1 tile_m x 16 tile_n strip)
  const int nm = M / BM, nn_t = N / BN;
  const int nwg = gridDim.x;
  const int bid = blockIdx.x;
  int tile_m, tile_n;
  if (nm == 32 && nn_t == 16 && nwg == 512) {
    int xcd = bid & 7;
    int j = bid >> 3;
    tile_m = (j >> 4) * 8 + xcd;
    tile_n = j & 15;
  } else {
    int swz = bid;
    if ((nwg & 7) == 0) swz = (bid & 7) * (nwg >> 3) + (bid >> 3);
    tile_m = swz % nm;
    tile_n = swz / nm;
  }
  const int bm = tile_m * BM;
  const int bn = tile_n * BN;

  // Precomputed swizzled LDS read bases (byte offsets from ldsB):
  // (row*128+col) ^ ((row&7)<<4)  ==  base + F*2048 + lk_kk  (verified R5)
  const int lk0 = r * 128 + ((q4 ^ (r & 3)) << 4) + ((((r >> 2) & 1)) << 6);
  const int lk1 = r * 128 + ((q4 ^ (r & 3)) << 4) + ((1 ^ ((r >> 2) & 1)) << 6);
  int offA[2][2], offB[2][2];
#pragma unroll
  for (int p = 0; p < 2; ++p) {
    offA[p][0] = (p * 4 + wr) * 16384 + lk0;
    offA[p][1] = (p * 4 + wr) * 16384 + lk1;
    offB[p][0] = (p * 4 + 2 + (wc >> 1)) * 16384 + (wc & 1) * 8192 + lk0;
    offB[p][1] = (p * 4 + 2 + (wc >> 1)) * 16384 + (wc & 1) * 8192 + lk1;
  }

  // Staging lane constants (linear LDS dest + inverse-swizzled global src)
  const int rl = lane >> 3;
  const int gs = (lane & 7) ^ (rl & 7);
  const int stOffB = w * 2048 + lane * 16;
  const size_t K8 = (size_t)8 * K;
  const size_t K128 = (size_t)128 * K;
  const unsigned short* gA_lane = A + (size_t)bm * K + (size_t)(w * 16 + rl) * K + gs * 8;
  const unsigned short* gB_lane = Wt + (size_t)bn * K + (size_t)(w * 16 + rl) * K + gs * 8;

  // ---- prologue: tile0 {A0,A1,B0,B1}, tile1 {B0,B1,A0}; then q0(tile0) ----
  stage2(gA_lane,              K8, (unsigned short*)(ldsB + 0 * 16384 + stOffB));
  stage2(gA_lane + K128,       K8, (unsigned short*)(ldsB + 1 * 16384 + stOffB));
  stage2(gB_lane,              K8, (unsigned short*)(ldsB + 2 * 16384 + stOffB));
  stage2(gB_lane + K128,       K8, (unsigned short*)(ldsB + 3 * 16384 + stOffB));
  WAIT_VM(4);
  stage2(gB_lane + BKT,        K8, (unsigned short*)(ldsB + 6 * 16384 + stOffB));
  stage2(gB_lane + K128 + BKT, K8, (unsigned short*)(ldsB + 7 * 16384 + stOffB));
  stage2(gA_lane + BKT,        K8, (unsigned short*)(ldsB + 4 * 16384 + stOffB));
  WAIT_VM(6);
  BAR();

  f32x4 acc[8][4] = {};
  bf16x8 bfr[4][2];
  bf16x8 aQ0[2][2], aQ1[2][2], aQ2[2][2], aQ3[2][2];

  RD_AQ(aQ0, 0, 0);   // tile0 quad0; stays in flight, drained at ph1's lgkm(4)

  for (int t = 0; t < NT; t += 2) {
    KT(t, 0);
    KT(t + 1, 1);
  }

  // ---- epilogue: out = acc * scales + bias --------------------------------
  float sc[4], bs[4];
#pragma unroll
  for (int ni = 0; ni < 4; ++ni) {
    int col = bn + wc * 64 + ni * 16 + r;
    sc[ni] = scales[col];
    bs[ni] = bias[col];
  }
#pragma unroll
  for (int mi = 0; mi < 8; ++mi)
#pragma unroll
    for (int ni = 0; ni < 4; ++ni)
#pragma unroll
      for (int i = 0; i < 4; ++i) {
        int grow = bm + wr * 128 + mi * 16 + q4 * 4 + i;
        int gcol = bn + wc * 64 + ni * 16 + r;
        out[(size_t)grow * N + gcol] = acc[mi][ni][i] * sc[ni] + bs[ni];
      }
}

// ---- fallback (correct but slow) ------------------------------------------
__global__ __launch_bounds__(256) void naive_kernel(
    const float* __restrict__ A, const int* __restrict__ W8,
    const float* __restrict__ scales, const float* __restrict__ bias,
    float* __restrict__ out, int M, int N, int K) {
  long idx = (long)blockIdx.x * 256 + threadIdx.x;
  if (idx >= (long)M * N) return;
  int m = (int)(idx / N), n = (int)(idx % N);
  const float* a = A + (size_t)m * K;
  const int* wv = W8 + (size_t)n * K;
  float s = 0.f;
  for (int k = 0; k < K; ++k) s += a[k] * (float)wv[k];
  out[idx] = s * scales[n] + bias[n];
}

extern "C" void kernel_launch(void* const* d_in, const int* in_sizes, int n_in,
                              void* d_out, int out_size, void* d_ws, size_t ws_size,
                              hipStream_t stream) {
  const float* A = (const float*)d_in[0];
  const int* W8 = (const int*)d_in[1];
  const float* scales = (const float*)d_in[2];
  const float* bias = (const float*)d_in[3];
  float* out = (float*)d_out;

  const int N = in_sizes[2];
  const int K = in_sizes[1] / N;
  const int M = in_sizes[0] / K;

  size_t a_bytes = (size_t)M * K * 2;
  size_t w_bytes = (size_t)N * K * 2;
  const int NT = K / BKT;

  bool tiled_ok = (M % BM == 0) && (N % BN == 0) && (K % BKT == 0) &&
                  (NT >= 4) && (NT % 2 == 0) && (ws_size >= a_bytes + w_bytes);

  if (!tiled_ok) {
    long total = (long)M * N;
    naive_kernel<<<(unsigned)((total + 255) / 256), 256, 0, stream>>>(
        A, W8, scales, bias, out, M, N, K);
    return;
  }

  unsigned short* Abf = (unsigned short*)d_ws;
  unsigned short* Wbf = (unsigned short*)((char*)d_ws + a_bytes);

  long nA = (long)M * K;
  long nW = (long)N * K;
  cvt_a_kernel<<<(unsigned)(nA / 2048), 256, 0, stream>>>(A, Abf);
  cvt_w_kernel<<<(unsigned)(nW / 2048), 256, 0, stream>>>(W8, Wbf);

  unsigned nwg = (unsigned)((M / BM) * (N / BN));  // 512
  gemm8_kernel<<<nwg, 512, 0, stream>>>(Abf, Wbf, scales, bias, out, M, N, K);
}